// Round 2
// 80.564 us; speedup vs baseline: 1.0150x; 1.0150x over previous
//
#include <hip/hip_runtime.h>

// SPLoPA adapter: out[r][c] = weights[r][c] + sum_k pos[k, r/32, c/32] * w[k, r%32] * h[k, c%32]
// weights: 2048x2048 f32; pos: (64,64,64) f32; proto_w: (64,32,1) f32; proto_h: (64,1,32) f32
//
// v2 structure (resubmit — round 1 failed on container acquisition, no signal):
//  - 512 blocks x 256 threads; each block = 4 waves; each wave computes TWO
//    column-adjacent 32x32 tiles (i, j0) and (i, j0+1). wv/hv LDS reads are
//    tile-independent, so this halves LDS-port pressure per output element
//    and doubles per-wave FMA ILP.
//  - pos is prefetched per-lane (lane k holds pos[k,i,j0..j0+1] via ONE
//    global_load_dwordx2) and broadcast in the k-loop with v_readlane_b32.
//    This removes all s_load/ds_read lgkmcnt mixing from the inner loop —
//    the loop is pure {2x ds_read_b128 + 42 VALU} per k.
//  - Each lane computes a 4x4 micro-tile per tile: a0 = (lane>>3)*4 rows,
//    b0 = (lane&7)*4 cols -> stores are 8 rows x 256B contiguous per wave.

#define KDIM 64

__global__ __launch_bounds__(256) void splopa_kernel(
    const float* __restrict__ weights,
    const float* __restrict__ pos,
    const float* __restrict__ pw,    // (64,32): w[k*32 + a]
    const float* __restrict__ ph,    // (64,32): h[k*32 + b]
    float* __restrict__ out)
{
    __shared__ float w_lds[KDIM * 32];
    __shared__ float h_lds[KDIM * 32];

    const int tid  = threadIdx.x;  // 0..255
    const int wave = tid >> 6;     // 0..3
    const int lane = tid & 63;

    const int tp = (blockIdx.x << 2) + wave;  // tile-pair id 0..2047
    const int i  = tp >> 5;                   // row tile 0..63
    const int j0 = (tp & 31) << 1;            // col tile 0,2,...,62
    int ij = (i << 6) + j0;
    ij = __builtin_amdgcn_readfirstlane(ij);

    // Per-lane pos prefetch: lane k holds {pos[k,i,j0], pos[k,i,j0+1]}.
    // Issued before staging so HBM latency overlaps the LDS fill + barrier.
    const float2 vpk = *(const float2*)&pos[((size_t)lane << 12) + ij];

    const int a0 = (lane >> 3) << 2;  // 0,4,...,28
    const int b0 = (lane & 7) << 2;   // 0,4,...,28

    const int row0 = (i << 5) + a0;
    const int col0 = (j0 << 5) + b0;
    const float* wptr = weights + (size_t)row0 * 2048 + col0;
    float*       optr = out     + (size_t)row0 * 2048 + col0;

    // Prefetch both 4x4 weights micro-tiles early.
    float4 wt00 = *(const float4*)(wptr);
    float4 wt01 = *(const float4*)(wptr + 2048);
    float4 wt02 = *(const float4*)(wptr + 4096);
    float4 wt03 = *(const float4*)(wptr + 6144);
    float4 wt10 = *(const float4*)(wptr + 32);
    float4 wt11 = *(const float4*)(wptr + 2048 + 32);
    float4 wt12 = *(const float4*)(wptr + 4096 + 32);
    float4 wt13 = *(const float4*)(wptr + 6144 + 32);

    // Stage w,h into LDS: 2048 floats = 512 float4 each; 256 threads x 2 iters.
    {
        const float4* wg = (const float4*)pw;
        const float4* hg = (const float4*)ph;
        float4* wl = (float4*)w_lds;
        float4* hl = (float4*)h_lds;
        wl[tid]       = wg[tid];
        wl[tid + 256] = wg[tid + 256];
        hl[tid]       = hg[tid];
        hl[tid + 256] = hg[tid + 256];
    }

    float4 a00 = {0.f,0.f,0.f,0.f}, a01 = {0.f,0.f,0.f,0.f};
    float4 a02 = {0.f,0.f,0.f,0.f}, a03 = {0.f,0.f,0.f,0.f};
    float4 a10 = {0.f,0.f,0.f,0.f}, a11 = {0.f,0.f,0.f,0.f};
    float4 a12 = {0.f,0.f,0.f,0.f}, a13 = {0.f,0.f,0.f,0.f};

    __syncthreads();

    #pragma unroll
    for (int k = 0; k < KDIM; ++k) {
        const float4 wv = *(const float4*)&w_lds[(k << 5) + a0]; // ds_read_b128, 8-way bcast
        const float4 hv = *(const float4*)&h_lds[(k << 5) + b0]; // ds_read_b128, 8-way bcast
        const float pk0 = __uint_as_float(
            __builtin_amdgcn_readlane(__float_as_uint(vpk.x), k)); // SGPR broadcast
        const float pk1 = __uint_as_float(
            __builtin_amdgcn_readlane(__float_as_uint(vpk.y), k));

        float t;
        t = pk0 * wv.x; a00.x += t*hv.x; a00.y += t*hv.y; a00.z += t*hv.z; a00.w += t*hv.w;
        t = pk0 * wv.y; a01.x += t*hv.x; a01.y += t*hv.y; a01.z += t*hv.z; a01.w += t*hv.w;
        t = pk0 * wv.z; a02.x += t*hv.x; a02.y += t*hv.y; a02.z += t*hv.z; a02.w += t*hv.w;
        t = pk0 * wv.w; a03.x += t*hv.x; a03.y += t*hv.y; a03.z += t*hv.z; a03.w += t*hv.w;
        t = pk1 * wv.x; a10.x += t*hv.x; a10.y += t*hv.y; a10.z += t*hv.z; a10.w += t*hv.w;
        t = pk1 * wv.y; a11.x += t*hv.x; a11.y += t*hv.y; a11.z += t*hv.z; a11.w += t*hv.w;
        t = pk1 * wv.z; a12.x += t*hv.x; a12.y += t*hv.y; a12.z += t*hv.z; a12.w += t*hv.w;
        t = pk1 * wv.w; a13.x += t*hv.x; a13.y += t*hv.y; a13.z += t*hv.z; a13.w += t*hv.w;
    }

    wt00.x += a00.x; wt00.y += a00.y; wt00.z += a00.z; wt00.w += a00.w;
    wt01.x += a01.x; wt01.y += a01.y; wt01.z += a01.z; wt01.w += a01.w;
    wt02.x += a02.x; wt02.y += a02.y; wt02.z += a02.z; wt02.w += a02.w;
    wt03.x += a03.x; wt03.y += a03.y; wt03.z += a03.z; wt03.w += a03.w;
    wt10.x += a10.x; wt10.y += a10.y; wt10.z += a10.z; wt10.w += a10.w;
    wt11.x += a11.x; wt11.y += a11.y; wt11.z += a11.z; wt11.w += a11.w;
    wt12.x += a12.x; wt12.y += a12.y; wt12.z += a12.z; wt12.w += a12.w;
    wt13.x += a13.x; wt13.y += a13.y; wt13.z += a13.z; wt13.w += a13.w;

    *(float4*)(optr)             = wt00;
    *(float4*)(optr + 2048)      = wt01;
    *(float4*)(optr + 4096)      = wt02;
    *(float4*)(optr + 6144)      = wt03;
    *(float4*)(optr + 32)        = wt10;
    *(float4*)(optr + 2048 + 32) = wt11;
    *(float4*)(optr + 4096 + 32) = wt12;
    *(float4*)(optr + 6144 + 32) = wt13;
}

extern "C" void kernel_launch(void* const* d_in, const int* in_sizes, int n_in,
                              void* d_out, int out_size, void* d_ws, size_t ws_size,
                              hipStream_t stream) {
    const float* weights = (const float*)d_in[0];  // 2048*2048
    const float* pos     = (const float*)d_in[1];  // 64*64*64
    const float* pw      = (const float*)d_in[2];  // 64*32*1
    const float* ph      = (const float*)d_in[3];  // 64*1*32
    float* out = (float*)d_out;                    // 2048*2048

    splopa_kernel<<<512, 256, 0, stream>>>(weights, pos, pw, ph, out);
}